// Round 11
// baseline (874.560 us; speedup 1.0000x reference)
//
#include <hip/hip_runtime.h>
#include <cstddef>
#include <cstdint>

// ---------------------------------------------------------------------------
// LogicRecursiveNN — Round 11 == Round 9 resubmit (R9/R10 were infra
// timeouts). Fit the deep pipeline UNDER the observed 128-VGPR cap (R7/R8
// evidence: 512-thr MFMA kernels get arch-VGPR capped at 128 regardless of
// launch_bounds; acc[8][4] designs spill ~100 regs).
// gemm_p: 256x128 tile, 8 waves of 64x64 (acc[4][4]=64 VGPR), BK=64,
// ring-of-3 LDS K-tiles (144 KiB), counted vmcnt(6), proven 128B-row swizzle.
//   per K-tile t (2 phases):
//     P1: RD(ks0) 8xds_read_b128 ; stage 3/6 ops of t+2 ; BAR ; 16 MFMA ; BAR
//     P2: RD(ks1)                ; stage 3/6 ops of t+2 ; vmcnt(6) [drains
//         t+1 exactly, leaves t+2 in flight] ; BAR ; 16 MFMA ; BAR
//   Ring-of-3: stage target buf (t+2)%3 was last read at tile t-1 -> safe.
// gemm128 (R4, proven) for tail levels / one2one / head.
// ---------------------------------------------------------------------------

typedef _Float16 f16;
typedef _Float16 f16x8 __attribute__((ext_vector_type(8)));
typedef float f32x4 __attribute__((ext_vector_type(4)));

__device__ __forceinline__ void gll16(const void* g, void* l) {
  __builtin_amdgcn_global_load_lds(
      (const __attribute__((address_space(1))) void*)g,
      (__attribute__((address_space(3))) void*)l, 16, 0, 0);
}

#define BAR __builtin_amdgcn_s_barrier()
#define VM6 asm volatile("s_waitcnt vmcnt(6)" ::: "memory")
#define VM0 asm volatile("s_waitcnt vmcnt(0)" ::: "memory")

// C[M,N] = relu(A[M,K] @ Bt[N,K]^T + bias), f16 in/out, f32 accum.
// M mult of 256, N mult of 128, K mult of 64.
// GATHER (K==1024): A row r = entf[lidx[2r + (k>>9)]][k&511].
template <int GATHER>
__global__ __launch_bounds__(512) void gemm_p(
    const f16* __restrict__ A, const f16* __restrict__ Bt,
    const float* __restrict__ bias, f16* __restrict__ C, int N, int K,
    const int* __restrict__ lidx, const f16* __restrict__ entf) {
  __shared__ __align__(16) f16 As[3][256][64];  // 96 KB, ring of 3 K-tiles
  __shared__ __align__(16) f16 Bs[3][128][64];  // 48 KB
  const int tid = threadIdx.x;
  const int m0 = blockIdx.y * 256;
  const int n0 = blockIdx.x * 128;

  // ---- staging: one op = 512 thr x 16B = 8KB = 64 rows x 128B.
  // A K-tile (256 rows) = 4 ops; B K-tile (128 rows) = 2 ops.
  // Source chunk pre-swizzled chunk^(row&7); read at cb ^ ((row&7)<<4)
  // (both-sides involution; R4/R5/R8-proven, 0 bank conflicts).
  const int srow = tid >> 3;                     // 0..63
  const int sk = ((tid & 7) ^ (srow & 7)) << 3;  // f16 elems
  const f16* Asrc = GATHER ? (const f16*)nullptr
                           : (A + (size_t)(m0 + srow) * K + sk);
  const f16* Bsrc = Bt + (size_t)(n0 + srow) * K + sk;
  const int wvb = (tid >> 6) * 1024;  // wave base; HW adds lane*16

  int e0[4], e1[4];  // gather entities per A-op (rows op*64 + srow)
  if (GATHER) {
#pragma unroll
    for (int r = 0; r < 4; ++r) {
      const int grow = m0 + r * 64 + srow;
      e0[r] = lidx[2 * grow];
      e1[r] = lidx[2 * grow + 1];
    }
  }

#define SA(S, R, KB)                                                    \
  {                                                                     \
    char* d_ = (char*)As + (size_t)(S)*32768 + (R)*8192 + wvb;          \
    if (!GATHER) {                                                      \
      gll16(Asrc + (size_t)((R)*64) * K + (KB), d_);                    \
    } else {                                                            \
      const int e_ = ((KB) >> 9) ? e1[R] : e0[R];                       \
      gll16(entf + ((size_t)e_ << 9) + (((KB)&511) + sk), d_);          \
    }                                                                   \
  }
#define SB(S, R, KB)                                                    \
  {                                                                     \
    char* d_ = (char*)Bs + (size_t)(S)*16384 + (R)*8192 + wvb;          \
    gll16(Bsrc + (size_t)((R)*64) * K + (KB), d_);                      \
  }

  // ---- fragments: 8 waves 4M x 2N; wave owns 64x64 = 4 m-frags x 4 n-frags
  const int l = tid & 63, wid = tid >> 6;
  const int wm = wid >> 1, wn = wid & 1;
  const int q = l & 15, kg = l >> 4;
  const int csw = (kg << 4) ^ ((q & 7) << 4);  // swizzled byte col, ks=0
  const char* Abase = (const char*)As + (wm * 64 + q) * 128;
  const char* Bbase = (const char*)Bs + (wn * 64 + q) * 128;

  f16x8 a[4], b[4];
  f32x4 acc[4][4] = {};

#define RD(S, KS)                                                       \
  {                                                                     \
    _Pragma("unroll") for (int i_ = 0; i_ < 4; ++i_)                    \
        a[i_] = *(const f16x8*)(Abase + (S)*32768 + i_ * 2048 +         \
                                (csw ^ ((KS) << 6)));                   \
    _Pragma("unroll") for (int j_ = 0; j_ < 4; ++j_)                    \
        b[j_] = *(const f16x8*)(Bbase + (S)*16384 + j_ * 2048 +         \
                                (csw ^ ((KS) << 6)));                   \
  }
#define MM                                                              \
  __builtin_amdgcn_s_setprio(1);                                        \
  {                                                                     \
    _Pragma("unroll") for (int i_ = 0; i_ < 4; ++i_) {                  \
      _Pragma("unroll") for (int j_ = 0; j_ < 4; ++j_) {                \
        acc[i_][j_] = __builtin_amdgcn_mfma_f32_16x16x32_f16(           \
            a[i_], b[j_], acc[i_][j_], 0, 0, 0);                        \
      }                                                                 \
    }                                                                   \
  }                                                                     \
  __builtin_amdgcn_s_setprio(0);

  // ---- prologue: stage tiles 0 and 1 (12 ops); vmcnt(6) -> t0 landed
  SA(0, 0, 0); SA(0, 1, 0); SA(0, 2, 0); SA(0, 3, 0); SB(0, 0, 0); SB(0, 1, 0);
  SA(1, 0, 64); SA(1, 1, 64); SA(1, 2, 64); SA(1, 3, 64);
  SB(1, 0, 64); SB(1, 1, 64);
  VM6; BAR;

  const int nt = K >> 6;
  int s = 0;  // t % 3
  for (int t = 0; t < nt; ++t) {
    const int s2 = (s + 2 >= 3) ? (s - 1) : (s + 2);  // (t+2) % 3
    const int kb2 = (t + 2) << 6;
    const bool pf = (t + 2) < nt;
    // P1: fragments ks0; stage A-ops 0..2 of t+2
    RD(s, 0);
    if (pf) { SA(s2, 0, kb2); SA(s2, 1, kb2); SA(s2, 2, kb2); }
    BAR; MM; BAR;
    // P2: fragments ks1; stage A-op3 + B-ops of t+2; counted drain of t+1
    RD(s, 1);
    if (pf) {
      SA(s2, 3, kb2); SB(s2, 0, kb2); SB(s2, 1, kb2);
      VM6;  // t+1's 6 ops forced complete; t+2's 6 stay in flight
    } else {
      VM0;
    }
    BAR; MM; BAR;
    s = (s + 1 == 3) ? 0 : (s + 1);
  }
#undef SA
#undef SB
#undef RD
#undef MM

  // ---- epilogue: row = wm*64 + i*16 + kg*4 + vi, col = wn*64 + j*16 + q
#pragma unroll
  for (int j = 0; j < 4; ++j) {
    const int col = n0 + wn * 64 + j * 16 + q;
    const float bsv = bias[col];
#pragma unroll
    for (int i = 0; i < 4; ++i) {
      f32x4 v = acc[i][j];
#pragma unroll
      for (int vi = 0; vi < 4; ++vi) {
        const int row = m0 + wm * 64 + i * 16 + kg * 4 + vi;
        C[(size_t)row * N + col] = (f16)fmaxf(v[vi] + bsv, 0.0f);
      }
    }
  }
}

// ---------------- 128x128 m97-structure kernel (tail levels / head) --------
template <int ACT, int OUTF32>
__global__ __launch_bounds__(256) void gemm128(
    const f16* __restrict__ A, const f16* __restrict__ Bt,
    const float* __restrict__ bias, void* __restrict__ Cout, int N, int K) {
  __shared__ __align__(16) f16 As[128 * 64];
  __shared__ __align__(16) f16 Bs[128 * 64];
  const int tid = threadIdx.x;
  const int m0 = blockIdx.y * 128;
  const int n0 = blockIdx.x * 128;
  const int srow = tid >> 3;
  const int sk = ((tid & 7) ^ ((tid >> 3) & 7)) << 3;
  const f16* Ag = A + (size_t)(m0 + srow) * K + sk;
  const f16* Bg = Bt + (size_t)(n0 + srow) * K + sk;
  char* Al = (char*)As + (tid >> 6) * 1024;
  char* Bl = (char*)Bs + (tid >> 6) * 1024;
  const int l = tid & 63;
  const int wm = tid >> 7;
  const int wn = (tid >> 6) & 1;
  const int q = l & 15;
  const int kg = l >> 4;
  const char* Ar = (const char*)As + (wm * 64 + q) * 128;
  const char* Br = (const char*)Bs + (wn * 64 + q) * 128;
  const int c0 = ((kg << 4) ^ ((q & 7) << 4));
  f32x4 acc[4][4] = {};
  for (int k0 = 0; k0 < K; k0 += 64) {
#pragma unroll
    for (int r = 0; r < 4; ++r) {
      gll16(Ag + (size_t)(r * 32) * K + k0, Al + r * 4096);
      gll16(Bg + (size_t)(r * 32) * K + k0, Bl + r * 4096);
    }
    __syncthreads();
#pragma unroll
    for (int ks = 0; ks < 2; ++ks) {
      const int cb = c0 ^ (ks << 6);
      f16x8 a[4], b[4];
#pragma unroll
      for (int i = 0; i < 4; ++i) a[i] = *(const f16x8*)(Ar + i * 2048 + cb);
#pragma unroll
      for (int j = 0; j < 4; ++j) b[j] = *(const f16x8*)(Br + j * 2048 + cb);
#pragma unroll
      for (int i = 0; i < 4; ++i)
#pragma unroll
        for (int j = 0; j < 4; ++j)
          acc[i][j] = __builtin_amdgcn_mfma_f32_16x16x32_f16(a[i], b[j],
                                                             acc[i][j], 0, 0, 0);
    }
    __syncthreads();
  }
#pragma unroll
  for (int j = 0; j < 4; ++j) {
    const int col = n0 + wn * 64 + j * 16 + q;
    const float bsv = bias[col];
#pragma unroll
    for (int i = 0; i < 4; ++i) {
      f32x4 v = acc[i][j];
#pragma unroll
      for (int vi = 0; vi < 4; ++vi) {
        const int row = m0 + wm * 64 + i * 16 + kg * 4 + vi;
        float c = v[vi] + bsv;
        if (ACT == 1) c = fmaxf(c, 0.0f);
        if (ACT == 2) c = tanhf(c);
        if (OUTF32)
          ((float*)Cout)[(size_t)row * N + col] = c;
        else
          ((f16*)Cout)[(size_t)row * N + col] = (f16)c;
      }
    }
  }
}

// dst[n][k] = (f16) src[k][n];  K,N multiples of 32
__global__ void transpose_cvt(const float* __restrict__ src,
                              f16* __restrict__ dst, int K, int N) {
  __shared__ f16 tile[32][33];
  const int k0 = blockIdx.x * 32, n0 = blockIdx.y * 32;
  const int tx = threadIdx.x & 31, ty = threadIdx.x >> 5;
  for (int r = ty; r < 32; r += 8)
    tile[r][tx] = (f16)src[(size_t)(k0 + r) * N + n0 + tx];
  __syncthreads();
  for (int r = ty; r < 32; r += 8)
    dst[(size_t)(n0 + r) * K + k0 + tx] = tile[tx][r];
}

// f32 -> f16 elementwise, 8 per thread
__global__ void cvt_f16(const float* __restrict__ src, f16* __restrict__ dst) {
  const int g = blockIdx.x * 256 + threadIdx.x;
  const float4* s = (const float4*)(src + (size_t)g * 8);
  float4 v0 = s[0], v1 = s[1];
  f16x8 o;
  o[0] = (f16)v0.x; o[1] = (f16)v0.y; o[2] = (f16)v0.z; o[3] = (f16)v0.w;
  o[4] = (f16)v1.x; o[5] = (f16)v1.y; o[6] = (f16)v1.z; o[7] = (f16)v1.w;
  *(f16x8*)(dst + (size_t)g * 8) = o;
}

__global__ void build_feat_h(const float* __restrict__ th,
                             const f16* __restrict__ root,
                             f16* __restrict__ feat) {
  int idx = blockIdx.x * 256 + threadIdx.x;  // 512*1536 total
  int b = idx / 1536;
  int c = idx - b * 1536;
  feat[idx] = (c < 512) ? (f16)th[c] : root[(size_t)b * 1024 + (c - 512)];
}

__global__ void head_final(const float* __restrict__ z3,
                           const float* __restrict__ h4,
                           const float* __restrict__ hb4,
                           float* __restrict__ out) {
  int row = blockIdx.x;
  int t = threadIdx.x;  // 64
  float v = z3[(size_t)row * 128 + t] * h4[t] +
            z3[(size_t)row * 128 + 64 + t] * h4[64 + t];
#pragma unroll
  for (int off = 32; off; off >>= 1) v += __shfl_down(v, off);
  if (t == 0) out[row] = 1.0f / (1.0f + expf(-(v + hb4[0])));
}

extern "C" void kernel_launch(void* const* d_in, const int* in_sizes, int n_in,
                              void* d_out, int out_size, void* d_ws,
                              size_t ws_size, hipStream_t stream) {
  const int* leaf_idx = (const int*)d_in[0];
  const float* ent_emb = (const float*)d_in[1];
  const float* th_emb = (const float*)d_in[2];
  const float* w1 = (const float*)d_in[3];
  const float* b1 = (const float*)d_in[4];
  const float* w2 = (const float*)d_in[5];
  const float* b2 = (const float*)d_in[6];
  const float* o1 = (const float*)d_in[7];
  const float* ob1 = (const float*)d_in[8];
  const float* o2 = (const float*)d_in[9];
  const float* ob2 = (const float*)d_in[10];
  const float* h1 = (const float*)d_in[11];
  const float* hb1 = (const float*)d_in[12];
  const float* h2 = (const float*)d_in[13];
  const float* hb2 = (const float*)d_in[14];
  const float* h3 = (const float*)d_in[15];
  const float* hb3 = (const float*)d_in[16];
  const float* h4 = (const float*)d_in[17];
  const float* hb4 = (const float*)d_in[18];
  float* out = (float*)d_out;

  char* p = (char*)d_ws;
  f16* w1t = (f16*)p;  p += (size_t)2048 * 1024 * 2;
  f16* w2t = (f16*)p;  p += (size_t)512 * 2048 * 2;
  f16* o1t = (f16*)p;  p += (size_t)2048 * 512 * 2;
  f16* o2t = (f16*)p;  p += (size_t)512 * 2048 * 2;
  f16* h1t = (f16*)p;  p += (size_t)512 * 1536 * 2;
  f16* h2t = (f16*)p;  p += (size_t)256 * 512 * 2;
  f16* h3t = (f16*)p;  p += (size_t)128 * 256 * 2;
  f16* entf = (f16*)p; p += (size_t)2000 * 512 * 2;
  f16* Hf   = (f16*)p; p += (size_t)32768 * 2048 * 2;  // 128 MB
  f16* bufA = (f16*)p; p += (size_t)32768 * 512 * 2;   // 32 MB
  f16* featf = (f16*)p; p += (size_t)512 * 1536 * 2;
  f16* z1h  = (f16*)p; p += (size_t)512 * 512 * 2;
  f16* z2h  = (f16*)p; p += (size_t)512 * 256 * 2;
  float* z3 = (float*)p; p += (size_t)512 * 128 * 4;
  // bufB overlays Hf's top half (per-level live region of Hf <= 64 MB then)
  f16* bufB = Hf + (size_t)32 * 1024 * 1024;

  // ---- prep
  transpose_cvt<<<dim3(1024 / 32, 2048 / 32), 256, 0, stream>>>(w1, w1t, 1024, 2048);
  transpose_cvt<<<dim3(2048 / 32, 512 / 32), 256, 0, stream>>>(w2, w2t, 2048, 512);
  transpose_cvt<<<dim3(512 / 32, 2048 / 32), 256, 0, stream>>>(o1, o1t, 512, 2048);
  transpose_cvt<<<dim3(2048 / 32, 512 / 32), 256, 0, stream>>>(o2, o2t, 2048, 512);
  transpose_cvt<<<dim3(1536 / 32, 512 / 32), 256, 0, stream>>>(h1, h1t, 1536, 512);
  transpose_cvt<<<dim3(512 / 32, 256 / 32), 256, 0, stream>>>(h2, h2t, 512, 256);
  transpose_cvt<<<dim3(256 / 32, 128 / 32), 256, 0, stream>>>(h3, h3t, 256, 128);
  cvt_f16<<<(2000 * 512) / 2048, 256, 0, stream>>>(ent_emb, entf);

  // ---- tree levels
  // L0 (M=32768): gather GEMM1 -> Hf (128 MB); GEMM2 -> bufA
  gemm_p<1><<<dim3(16, 128), 512, 0, stream>>>(nullptr, w1t, b1, Hf, 2048,
                                               1024, leaf_idx, entf);
  gemm_p<0><<<dim3(4, 128), 512, 0, stream>>>(Hf, w2t, b2, bufA, 512, 2048,
                                              nullptr, nullptr);
  // L1 (M=16384): GEMM1 -> Hf[0:64MB]; GEMM2 (128^2) -> bufB (@Hf+64MB)
  gemm_p<0><<<dim3(16, 64), 512, 0, stream>>>(bufA, w1t, b1, Hf, 2048, 1024,
                                              nullptr, nullptr);
  gemm128<1, 0><<<dim3(4, 128), 256, 0, stream>>>(Hf, w2t, b2, bufB, 512, 2048);
  // L2 (M=8192): GEMM1 -> Hf[0:32MB]; GEMM2 -> bufA
  gemm_p<0><<<dim3(16, 32), 512, 0, stream>>>(bufB, w1t, b1, Hf, 2048, 1024,
                                              nullptr, nullptr);
  gemm128<1, 0><<<dim3(4, 64), 256, 0, stream>>>(Hf, w2t, b2, bufA, 512, 2048);
  // L3 (M=4096)
  gemm128<1, 0><<<dim3(16, 32), 256, 0, stream>>>(bufA, w1t, b1, Hf, 2048, 1024);
  gemm128<1, 0><<<dim3(4, 32), 256, 0, stream>>>(Hf, w2t, b2, bufB, 512, 2048);
  // L4 (M=2048)
  gemm128<1, 0><<<dim3(16, 16), 256, 0, stream>>>(bufB, w1t, b1, Hf, 2048, 1024);
  gemm128<1, 0><<<dim3(4, 16), 256, 0, stream>>>(Hf, w2t, b2, bufA, 512, 2048);
  // L5 (M=1024)
  gemm128<1, 0><<<dim3(16, 8), 256, 0, stream>>>(bufA, w1t, b1, Hf, 2048, 1024);
  gemm128<1, 0><<<dim3(4, 8), 256, 0, stream>>>(Hf, w2t, b2, bufB, 512, 2048);

  // ---- one2one: relu(root@o1) -> tanh(..@o2); root = bufB [1024,512]
  gemm128<1, 0><<<dim3(16, 8), 256, 0, stream>>>(bufB, o1t, ob1, Hf, 2048, 512);
  gemm128<2, 0><<<dim3(4, 8), 256, 0, stream>>>(Hf, o2t, ob2, bufA, 512, 2048);

  // ---- head (f16 MFMA), root f16 = bufA [1024,512]
  build_feat_h<<<(512 * 1536) / 256, 256, 0, stream>>>(th_emb, bufA, featf);
  gemm128<1, 0><<<dim3(4, 4), 256, 0, stream>>>(featf, h1t, hb1, z1h, 512, 1536);
  gemm128<1, 0><<<dim3(2, 4), 256, 0, stream>>>(z1h, h2t, hb2, z2h, 256, 512);
  gemm128<1, 1><<<dim3(1, 4), 256, 0, stream>>>(z2h, h3t, hb3, z3, 128, 256);
  head_final<<<512, 64, 0, stream>>>(z3, h4, hb4, out);
}

// Round 14
// 859.429 us; speedup vs baseline: 1.0176x; 1.0176x over previous
//
#include <hip/hip_runtime.h>
#include <cstddef>
#include <cstdint>

// ---------------------------------------------------------------------------
// LogicRecursiveNN — Round 14 == Round 12 resubmit (R12 GPU-timeout, R13
// container-failure; the single-barrier diff is still unmeasured).
// gemm_p with ONE barrier per K-tile (was 4).
// R11 post-mortem: spill fixed (VGPR 88, WRITE=output) but MfmaUtil stuck at
// 35% — the pre-MFMA barriers serialized the CU into LDS-burst / MFMA-burst
// lockstep. Ring-of-3 makes the pre-MFMA barrier unnecessary: MFMA reads regs
// only; buffer staged at t is read at t+2, ordered by VM6@t+1 + 2 tile-end
// barriers; a wave's ds_reads of s complete before its own MFMA (data dep)
// which precedes the tile-end BAR which precedes any restage of s.
//   per K-tile t:  RD(ks0); MM; RD(ks1); stage 6 ops(t+2); MM; VM6; BAR
// (VM6 after the 2nd MFMA cluster so the drain hides under it.)
// Also: L1-G2 and L3-G1 (256-block grids) moved gemm128 -> gemm_p.
// gemm128 (R4, proven) for remaining tail levels / one2one / head.
// ---------------------------------------------------------------------------

typedef _Float16 f16;
typedef _Float16 f16x8 __attribute__((ext_vector_type(8)));
typedef float f32x4 __attribute__((ext_vector_type(4)));

__device__ __forceinline__ void gll16(const void* g, void* l) {
  __builtin_amdgcn_global_load_lds(
      (const __attribute__((address_space(1))) void*)g,
      (__attribute__((address_space(3))) void*)l, 16, 0, 0);
}

#define BAR __builtin_amdgcn_s_barrier()
#define VM6 asm volatile("s_waitcnt vmcnt(6)" ::: "memory")
#define VM0 asm volatile("s_waitcnt vmcnt(0)" ::: "memory")

// C[M,N] = relu(A[M,K] @ Bt[N,K]^T + bias), f16 in/out, f32 accum.
// M mult of 256, N mult of 128, K mult of 64.
// GATHER (K==1024): A row r = entf[lidx[2r + (k>>9)]][k&511].
template <int GATHER>
__global__ __launch_bounds__(512) void gemm_p(
    const f16* __restrict__ A, const f16* __restrict__ Bt,
    const float* __restrict__ bias, f16* __restrict__ C, int N, int K,
    const int* __restrict__ lidx, const f16* __restrict__ entf) {
  __shared__ __align__(16) f16 As[3][256][64];  // 96 KB, ring of 3 K-tiles
  __shared__ __align__(16) f16 Bs[3][128][64];  // 48 KB
  const int tid = threadIdx.x;
  const int m0 = blockIdx.y * 256;
  const int n0 = blockIdx.x * 128;

  // ---- staging: one op = 512 thr x 16B = 8KB = 64 rows x 128B.
  // A K-tile (256 rows) = 4 ops; B K-tile (128 rows) = 2 ops.
  // Source chunk pre-swizzled chunk^(row&7); read at cb ^ ((row&7)<<4)
  // (both-sides involution; R4/R5/R8/R11-proven, 0 bank conflicts).
  const int srow = tid >> 3;                     // 0..63
  const int sk = ((tid & 7) ^ (srow & 7)) << 3;  // f16 elems
  const f16* Asrc = GATHER ? (const f16*)nullptr
                           : (A + (size_t)(m0 + srow) * K + sk);
  const f16* Bsrc = Bt + (size_t)(n0 + srow) * K + sk;
  const int wvb = (tid >> 6) * 1024;  // wave base; HW adds lane*16

  int e0[4], e1[4];  // gather entities per A-op (rows op*64 + srow)
  if (GATHER) {
#pragma unroll
    for (int r = 0; r < 4; ++r) {
      const int grow = m0 + r * 64 + srow;
      e0[r] = lidx[2 * grow];
      e1[r] = lidx[2 * grow + 1];
    }
  }

#define SA(S, R, KB)                                                    \
  {                                                                     \
    char* d_ = (char*)As + (size_t)(S)*32768 + (R)*8192 + wvb;          \
    if (!GATHER) {                                                      \
      gll16(Asrc + (size_t)((R)*64) * K + (KB), d_);                    \
    } else {                                                            \
      const int e_ = ((KB) >> 9) ? e1[R] : e0[R];                       \
      gll16(entf + ((size_t)e_ << 9) + (((KB)&511) + sk), d_);          \
    }                                                                   \
  }
#define SB(S, R, KB)                                                    \
  {                                                                     \
    char* d_ = (char*)Bs + (size_t)(S)*16384 + (R)*8192 + wvb;          \
    gll16(Bsrc + (size_t)((R)*64) * K + (KB), d_);                      \
  }

  // ---- fragments: 8 waves 4M x 2N; wave owns 64x64 = 4 m-frags x 4 n-frags
  const int l = tid & 63, wid = tid >> 6;
  const int wm = wid >> 1, wn = wid & 1;
  const int q = l & 15, kg = l >> 4;
  const int csw = (kg << 4) ^ ((q & 7) << 4);  // swizzled byte col, ks=0
  const char* Abase = (const char*)As + (wm * 64 + q) * 128;
  const char* Bbase = (const char*)Bs + (wn * 64 + q) * 128;

  f16x8 a[4], b[4];
  f32x4 acc[4][4] = {};

#define RD(S, KS)                                                       \
  {                                                                     \
    _Pragma("unroll") for (int i_ = 0; i_ < 4; ++i_)                    \
        a[i_] = *(const f16x8*)(Abase + (S)*32768 + i_ * 2048 +         \
                                (csw ^ ((KS) << 6)));                   \
    _Pragma("unroll") for (int j_ = 0; j_ < 4; ++j_)                    \
        b[j_] = *(const f16x8*)(Bbase + (S)*16384 + j_ * 2048 +         \
                                (csw ^ ((KS) << 6)));                   \
  }
#define MM                                                              \
  __builtin_amdgcn_s_setprio(1);                                        \
  {                                                                     \
    _Pragma("unroll") for (int i_ = 0; i_ < 4; ++i_) {                  \
      _Pragma("unroll") for (int j_ = 0; j_ < 4; ++j_) {                \
        acc[i_][j_] = __builtin_amdgcn_mfma_f32_16x16x32_f16(           \
            a[i_], b[j_], acc[i_][j_], 0, 0, 0);                        \
      }                                                                 \
    }                                                                   \
  }                                                                     \
  __builtin_amdgcn_s_setprio(0);

  // ---- prologue: stage tiles 0 and 1 (12 ops); vmcnt(6) -> t0 landed
  SA(0, 0, 0); SA(0, 1, 0); SA(0, 2, 0); SA(0, 3, 0); SB(0, 0, 0); SB(0, 1, 0);
  SA(1, 0, 64); SA(1, 1, 64); SA(1, 2, 64); SA(1, 3, 64);
  SB(1, 0, 64); SB(1, 1, 64);
  VM6; BAR;

  const int nt = K >> 6;
  int s = 0;  // t % 3
  for (int t = 0; t < nt; ++t) {
    const int s2 = (s + 2 >= 3) ? (s - 1) : (s + 2);  // (t+2) % 3
    const int kb2 = (t + 2) << 6;
    const bool pf = (t + 2) < nt;
    // one phase per K-tile: reads and MFMA of different waves overlap freely
    RD(s, 0);
    MM;
    RD(s, 1);
    if (pf) {
      SA(s2, 0, kb2); SA(s2, 1, kb2); SA(s2, 2, kb2); SA(s2, 3, kb2);
      SB(s2, 0, kb2); SB(s2, 1, kb2);
    }
    MM;
    if (pf) { VM6; } else { VM0; }  // drain t+1's 6 ops; t+2's stay in flight
    BAR;
    s = (s + 1 == 3) ? 0 : (s + 1);
  }
#undef SA
#undef SB
#undef RD
#undef MM

  // ---- epilogue: row = wm*64 + i*16 + kg*4 + vi, col = wn*64 + j*16 + q
#pragma unroll
  for (int j = 0; j < 4; ++j) {
    const int col = n0 + wn * 64 + j * 16 + q;
    const float bsv = bias[col];
#pragma unroll
    for (int i = 0; i < 4; ++i) {
      f32x4 v = acc[i][j];
#pragma unroll
      for (int vi = 0; vi < 4; ++vi) {
        const int row = m0 + wm * 64 + i * 16 + kg * 4 + vi;
        C[(size_t)row * N + col] = (f16)fmaxf(v[vi] + bsv, 0.0f);
      }
    }
  }
}

// ---------------- 128x128 m97-structure kernel (tail levels / head) --------
template <int ACT, int OUTF32>
__global__ __launch_bounds__(256) void gemm128(
    const f16* __restrict__ A, const f16* __restrict__ Bt,
    const float* __restrict__ bias, void* __restrict__ Cout, int N, int K) {
  __shared__ __align__(16) f16 As[128 * 64];
  __shared__ __align__(16) f16 Bs[128 * 64];
  const int tid = threadIdx.x;
  const int m0 = blockIdx.y * 128;
  const int n0 = blockIdx.x * 128;
  const int srow = tid >> 3;
  const int sk = ((tid & 7) ^ ((tid >> 3) & 7)) << 3;
  const f16* Ag = A + (size_t)(m0 + srow) * K + sk;
  const f16* Bg = Bt + (size_t)(n0 + srow) * K + sk;
  char* Al = (char*)As + (tid >> 6) * 1024;
  char* Bl = (char*)Bs + (tid >> 6) * 1024;
  const int l = tid & 63;
  const int wm = tid >> 7;
  const int wn = (tid >> 6) & 1;
  const int q = l & 15;
  const int kg = l >> 4;
  const char* Ar = (const char*)As + (wm * 64 + q) * 128;
  const char* Br = (const char*)Bs + (wn * 64 + q) * 128;
  const int c0 = ((kg << 4) ^ ((q & 7) << 4));
  f32x4 acc[4][4] = {};
  for (int k0 = 0; k0 < K; k0 += 64) {
#pragma unroll
    for (int r = 0; r < 4; ++r) {
      gll16(Ag + (size_t)(r * 32) * K + k0, Al + r * 4096);
      gll16(Bg + (size_t)(r * 32) * K + k0, Bl + r * 4096);
    }
    __syncthreads();
#pragma unroll
    for (int ks = 0; ks < 2; ++ks) {
      const int cb = c0 ^ (ks << 6);
      f16x8 a[4], b[4];
#pragma unroll
      for (int i = 0; i < 4; ++i) a[i] = *(const f16x8*)(Ar + i * 2048 + cb);
#pragma unroll
      for (int j = 0; j < 4; ++j) b[j] = *(const f16x8*)(Br + j * 2048 + cb);
#pragma unroll
      for (int i = 0; i < 4; ++i)
#pragma unroll
        for (int j = 0; j < 4; ++j)
          acc[i][j] = __builtin_amdgcn_mfma_f32_16x16x32_f16(a[i], b[j],
                                                             acc[i][j], 0, 0, 0);
    }
    __syncthreads();
  }
#pragma unroll
  for (int j = 0; j < 4; ++j) {
    const int col = n0 + wn * 64 + j * 16 + q;
    const float bsv = bias[col];
#pragma unroll
    for (int i = 0; i < 4; ++i) {
      f32x4 v = acc[i][j];
#pragma unroll
      for (int vi = 0; vi < 4; ++vi) {
        const int row = m0 + wm * 64 + i * 16 + kg * 4 + vi;
        float c = v[vi] + bsv;
        if (ACT == 1) c = fmaxf(c, 0.0f);
        if (ACT == 2) c = tanhf(c);
        if (OUTF32)
          ((float*)Cout)[(size_t)row * N + col] = c;
        else
          ((f16*)Cout)[(size_t)row * N + col] = (f16)c;
      }
    }
  }
}

// dst[n][k] = (f16) src[k][n];  K,N multiples of 32
__global__ void transpose_cvt(const float* __restrict__ src,
                              f16* __restrict__ dst, int K, int N) {
  __shared__ f16 tile[32][33];
  const int k0 = blockIdx.x * 32, n0 = blockIdx.y * 32;
  const int tx = threadIdx.x & 31, ty = threadIdx.x >> 5;
  for (int r = ty; r < 32; r += 8)
    tile[r][tx] = (f16)src[(size_t)(k0 + r) * N + n0 + tx];
  __syncthreads();
  for (int r = ty; r < 32; r += 8)
    dst[(size_t)(n0 + r) * K + k0 + tx] = tile[tx][r];
}

// f32 -> f16 elementwise, 8 per thread
__global__ void cvt_f16(const float* __restrict__ src, f16* __restrict__ dst) {
  const int g = blockIdx.x * 256 + threadIdx.x;
  const float4* s = (const float4*)(src + (size_t)g * 8);
  float4 v0 = s[0], v1 = s[1];
  f16x8 o;
  o[0] = (f16)v0.x; o[1] = (f16)v0.y; o[2] = (f16)v0.z; o[3] = (f16)v0.w;
  o[4] = (f16)v1.x; o[5] = (f16)v1.y; o[6] = (f16)v1.z; o[7] = (f16)v1.w;
  *(f16x8*)(dst + (size_t)g * 8) = o;
}

__global__ void build_feat_h(const float* __restrict__ th,
                             const f16* __restrict__ root,
                             f16* __restrict__ feat) {
  int idx = blockIdx.x * 256 + threadIdx.x;  // 512*1536 total
  int b = idx / 1536;
  int c = idx - b * 1536;
  feat[idx] = (c < 512) ? (f16)th[c] : root[(size_t)b * 1024 + (c - 512)];
}

__global__ void head_final(const float* __restrict__ z3,
                           const float* __restrict__ h4,
                           const float* __restrict__ hb4,
                           float* __restrict__ out) {
  int row = blockIdx.x;
  int t = threadIdx.x;  // 64
  float v = z3[(size_t)row * 128 + t] * h4[t] +
            z3[(size_t)row * 128 + 64 + t] * h4[64 + t];
#pragma unroll
  for (int off = 32; off; off >>= 1) v += __shfl_down(v, off);
  if (t == 0) out[row] = 1.0f / (1.0f + expf(-(v + hb4[0])));
}

extern "C" void kernel_launch(void* const* d_in, const int* in_sizes, int n_in,
                              void* d_out, int out_size, void* d_ws,
                              size_t ws_size, hipStream_t stream) {
  const int* leaf_idx = (const int*)d_in[0];
  const float* ent_emb = (const float*)d_in[1];
  const float* th_emb = (const float*)d_in[2];
  const float* w1 = (const float*)d_in[3];
  const float* b1 = (const float*)d_in[4];
  const float* w2 = (const float*)d_in[5];
  const float* b2 = (const float*)d_in[6];
  const float* o1 = (const float*)d_in[7];
  const float* ob1 = (const float*)d_in[8];
  const float* o2 = (const float*)d_in[9];
  const float* ob2 = (const float*)d_in[10];
  const float* h1 = (const float*)d_in[11];
  const float* hb1 = (const float*)d_in[12];
  const float* h2 = (const float*)d_in[13];
  const float* hb2 = (const float*)d_in[14];
  const float* h3 = (const float*)d_in[15];
  const float* hb3 = (const float*)d_in[16];
  const float* h4 = (const float*)d_in[17];
  const float* hb4 = (const float*)d_in[18];
  float* out = (float*)d_out;

  char* p = (char*)d_ws;
  f16* w1t = (f16*)p;  p += (size_t)2048 * 1024 * 2;
  f16* w2t = (f16*)p;  p += (size_t)512 * 2048 * 2;
  f16* o1t = (f16*)p;  p += (size_t)2048 * 512 * 2;
  f16* o2t = (f16*)p;  p += (size_t)512 * 2048 * 2;
  f16* h1t = (f16*)p;  p += (size_t)512 * 1536 * 2;
  f16* h2t = (f16*)p;  p += (size_t)256 * 512 * 2;
  f16* h3t = (f16*)p;  p += (size_t)128 * 256 * 2;
  f16* entf = (f16*)p; p += (size_t)2000 * 512 * 2;
  f16* Hf   = (f16*)p; p += (size_t)32768 * 2048 * 2;  // 128 MB
  f16* bufA = (f16*)p; p += (size_t)32768 * 512 * 2;   // 32 MB
  f16* featf = (f16*)p; p += (size_t)512 * 1536 * 2;
  f16* z1h  = (f16*)p; p += (size_t)512 * 512 * 2;
  f16* z2h  = (f16*)p; p += (size_t)512 * 256 * 2;
  float* z3 = (float*)p; p += (size_t)512 * 128 * 4;
  // bufB overlays Hf's top half (per-level live region of Hf <= 64 MB then)
  f16* bufB = Hf + (size_t)32 * 1024 * 1024;

  // ---- prep
  transpose_cvt<<<dim3(1024 / 32, 2048 / 32), 256, 0, stream>>>(w1, w1t, 1024, 2048);
  transpose_cvt<<<dim3(2048 / 32, 512 / 32), 256, 0, stream>>>(w2, w2t, 2048, 512);
  transpose_cvt<<<dim3(512 / 32, 2048 / 32), 256, 0, stream>>>(o1, o1t, 512, 2048);
  transpose_cvt<<<dim3(2048 / 32, 512 / 32), 256, 0, stream>>>(o2, o2t, 2048, 512);
  transpose_cvt<<<dim3(1536 / 32, 512 / 32), 256, 0, stream>>>(h1, h1t, 1536, 512);
  transpose_cvt<<<dim3(512 / 32, 256 / 32), 256, 0, stream>>>(h2, h2t, 512, 256);
  transpose_cvt<<<dim3(256 / 32, 128 / 32), 256, 0, stream>>>(h3, h3t, 256, 128);
  cvt_f16<<<(2000 * 512) / 2048, 256, 0, stream>>>(ent_emb, entf);

  // ---- tree levels
  // L0 (M=32768): gather GEMM1 -> Hf (128 MB); GEMM2 -> bufA
  gemm_p<1><<<dim3(16, 128), 512, 0, stream>>>(nullptr, w1t, b1, Hf, 2048,
                                               1024, leaf_idx, entf);
  gemm_p<0><<<dim3(4, 128), 512, 0, stream>>>(Hf, w2t, b2, bufA, 512, 2048,
                                              nullptr, nullptr);
  // L1 (M=16384): GEMM1 -> Hf[0:64MB]; GEMM2 -> bufB (@Hf+64MB)
  gemm_p<0><<<dim3(16, 64), 512, 0, stream>>>(bufA, w1t, b1, Hf, 2048, 1024,
                                              nullptr, nullptr);
  gemm_p<0><<<dim3(4, 64), 512, 0, stream>>>(Hf, w2t, b2, bufB, 512, 2048,
                                             nullptr, nullptr);
  // L2 (M=8192): GEMM1 -> Hf[0:32MB]; GEMM2 -> bufA
  gemm_p<0><<<dim3(16, 32), 512, 0, stream>>>(bufB, w1t, b1, Hf, 2048, 1024,
                                              nullptr, nullptr);
  gemm128<1, 0><<<dim3(4, 64), 256, 0, stream>>>(Hf, w2t, b2, bufA, 512, 2048);
  // L3 (M=4096): GEMM1 -> gemm_p (256 blocks); GEMM2 -> gemm128
  gemm_p<0><<<dim3(16, 16), 512, 0, stream>>>(bufA, w1t, b1, Hf, 2048, 1024,
                                              nullptr, nullptr);
  gemm128<1, 0><<<dim3(4, 32), 256, 0, stream>>>(Hf, w2t, b2, bufB, 512, 2048);
  // L4 (M=2048)
  gemm128<1, 0><<<dim3(16, 16), 256, 0, stream>>>(bufB, w1t, b1, Hf, 2048, 1024);
  gemm128<1, 0><<<dim3(4, 16), 256, 0, stream>>>(Hf, w2t, b2, bufA, 512, 2048);
  // L5 (M=1024)
  gemm128<1, 0><<<dim3(16, 8), 256, 0, stream>>>(bufA, w1t, b1, Hf, 2048, 1024);
  gemm128<1, 0><<<dim3(4, 8), 256, 0, stream>>>(Hf, w2t, b2, bufB, 512, 2048);

  // ---- one2one: relu(root@o1) -> tanh(..@o2); root = bufB [1024,512]
  gemm128<1, 0><<<dim3(16, 8), 256, 0, stream>>>(bufB, o1t, ob1, Hf, 2048, 512);
  gemm128<2, 0><<<dim3(4, 8), 256, 0, stream>>>(Hf, o2t, ob2, bufA, 512, 2048);

  // ---- head (f16 MFMA), root f16 = bufA [1024,512]
  build_feat_h<<<(512 * 1536) / 256, 256, 0, stream>>>(th_emb, bufA, featf);
  gemm128<1, 0><<<dim3(4, 4), 256, 0, stream>>>(featf, h1t, hb1, z1h, 512, 1536);
  gemm128<1, 0><<<dim3(2, 4), 256, 0, stream>>>(z1h, h2t, hb2, z2h, 256, 512);
  gemm128<1, 1><<<dim3(1, 4), 256, 0, stream>>>(z2h, h3t, hb3, z3, 128, 256);
  head_final<<<512, 64, 0, stream>>>(z3, h4, hb4, out);
}